// Round 6
// baseline (1041.283 us; speedup 1.0000x reference)
//
#include <hip/hip_runtime.h>
#include <cstdint>
#include <math.h>

// Problem constants
#define B_   4
#define T_   2048
#define D_   1024
#define H_   8
#define DK_  128
#define P_   4095   // 2T-1
#define PS_  4096   // padded P rows per head (row 4095 = finite junk, never consumed)

typedef unsigned short ushort_t;
typedef __attribute__((ext_vector_type(8))) short short8;
typedef __attribute__((ext_vector_type(4))) float floatx4;

__device__ inline float bf2f(ushort_t s) {
    return __uint_as_float(((unsigned int)s) << 16);
}
__device__ inline ushort_t f2bf(float f) {
    unsigned int u = __float_as_uint(f);
    u += 0x7fffu + ((u >> 16) & 1u);   // round-to-nearest-even
    return (ushort_t)(u >> 16);
}

__device__ inline floatx4 mfma16(short8 a, short8 b, floatx4 c) {
    return __builtin_amdgcn_mfma_f32_16x16x32_bf16(a, b, c, 0, 0, 0);
}

// async global->LDS, 16B per lane; LDS dest = wave-uniform base + lane*16
__device__ inline void gload_lds16(const ushort_t* g, ushort_t* l) {
    __builtin_amdgcn_global_load_lds(
        (const __attribute__((address_space(1))) unsigned int*)g,
        (__attribute__((address_space(3))) unsigned int*)l, 16, 0, 0);
}

// 16-lane (DPP-row) max reduction on the VALU pipe (keeps LDS pipe free).
// ror8 -> ror4 -> quad_perm xor2 -> quad_perm xor1 = full 16-lane all-reduce.
__device__ inline float rowmax16(float x) {
    int t;
    t = __builtin_amdgcn_update_dpp(0, __float_as_int(x), 0x128, 0xf, 0xf, true); // row_ror:8
    x = fmaxf(x, __int_as_float(t));
    t = __builtin_amdgcn_update_dpp(0, __float_as_int(x), 0x124, 0xf, 0xf, true); // row_ror:4
    x = fmaxf(x, __int_as_float(t));
    t = __builtin_amdgcn_update_dpp(0, __float_as_int(x), 0x4E, 0xf, 0xf, true);  // quad_perm xor2
    x = fmaxf(x, __int_as_float(t));
    t = __builtin_amdgcn_update_dpp(0, __float_as_int(x), 0xB1, 0xf, 0xf, true);  // quad_perm xor1
    x = fmaxf(x, __int_as_float(t));
    return x;
}

// dtype detector: flag 0 = bf16 inputs, 1 = fp32 inputs.
__global__ void detect_kernel(const ushort_t* x, int* flag) {
    if (blockIdx.x == 0 && threadIdx.x == 0) {
        int m = 0;
        for (int i = 0; i < 64; ++i) {
            float v = bf2f(x[2 * i]);
            float a = fabsf(v);
            if (!(a == 0.0f || (a > 1e-20f && a < 1e10f))) m = 1;
        }
        flag[0] = m;
    }
}

// ---------------------------------------------------------------------------
// Conversion: all external tensors -> contiguous bf16 arena (see r4 offsets).
// ---------------------------------------------------------------------------
#define CV_TOT 17826816
template <int MODE>
__global__ __launch_bounds__(256) void convert_kernel(
    const int* __restrict__ flag,
    const void* __restrict__ x, const void* __restrict__ pe,
    const void* __restrict__ wq, const void* __restrict__ wk,
    const void* __restrict__ wv, const void* __restrict__ wo,
    const void* __restrict__ wp, const void* __restrict__ ub,
    const void* __restrict__ vb, ushort_t* __restrict__ dst)
{
    if (flag[0] != MODE) return;
    const size_t i = ((size_t)blockIdx.x * 256 + threadIdx.x) * 4;
    if (i >= CV_TOT) return;
    const void* s; size_t off;
    if (i < 8388608)       { s = x;  off = i; }
    else if (i < 12581888) { s = pe; off = i - 8388608; }
    else if (i < 13630464) { s = wq; off = i - 12581888; }
    else if (i < 14679040) { s = wk; off = i - 13630464; }
    else if (i < 15727616) { s = wv; off = i - 14679040; }
    else if (i < 16776192) { s = wo; off = i - 15727616; }
    else if (i < 17824768) { s = wp; off = i - 16776192; }
    else if (i < 17825792) { s = ub; off = i - 17824768; }
    else                   { s = vb; off = i - 17825792; }
    const size_t d = i + (i >= 12581888 ? 1024 : 0);
    if (MODE == 0) {
        *(uint2*)(dst + d) = *(const uint2*)((const ushort_t*)s + off);
    } else {
        float4 f = *(const float4*)((const float*)s + off);
        uint2 o;
        o.x = (unsigned)f2bf(f.x) | ((unsigned)f2bf(f.y) << 16);
        o.y = (unsigned)f2bf(f.z) | ((unsigned)f2bf(f.w) << 16);
        *(uint2*)(dst + d) = o;
    }
}

// ---------------------------------------------------------------------------
// MFMA GEMM: C[m,n] = sum_k A[m,k]*W[n,k], A[M,1024], W[1024,1024] bf16.
// 128x128 tile, BK=64, 4 waves 2x2 (each 64x64 = 4x4 mfma tiles).
// LDS in FRAGMENT ORDER: tile stored as 16 chunks of 1KB; chunk (mg,ks)
// holds A-frag rows mg*16..+15, k-slice ks*32..+31 with element
// (row=lane&15, k=ks*32+(lane>>4)*8+j) at chunk_base + lane*16B.
// All ds_read_b128 are then base+lane*16 (conflict-free).
// smode: 0 -> [B,H,T,DK]; 1 -> [H,PS,DK]; 2 -> [B,H,DK,T];
//        3 -> row-major bf16 (iff flag==0); 4 -> row-major fp32 (iff flag==1)
// ---------------------------------------------------------------------------
__global__ __launch_bounds__(256, 3) void gemm_mfma(
    const int* __restrict__ flag,
    const ushort_t* __restrict__ A, const ushort_t* __restrict__ W,
    void* __restrict__ C, int smode)
{
    if (smode == 3 && flag[0] != 0) return;
    if (smode == 4 && flag[0] != 1) return;
    const int K = 1024, N = 1024;

    __shared__ ushort_t Al[16 * 512];   // 16 chunks x 512 ushorts (16KB)
    __shared__ ushort_t Wl[16 * 512];

    const int tid  = threadIdx.x;
    const int w    = tid >> 6, lane = tid & 63;
    const int r15  = lane & 15, quad = lane >> 4;
    const int wm   = w >> 1, wn = w & 1;
    const int m0   = blockIdx.y * 128, n0 = blockIdx.x * 128;

    floatx4 acc[4][4];
    const floatx4 z4 = {0.f, 0.f, 0.f, 0.f};
#pragma unroll
    for (int mt = 0; mt < 4; ++mt)
#pragma unroll
        for (int nt = 0; nt < 4; ++nt) acc[mt][nt] = z4;

    for (int k0 = 0; k0 < K; k0 += 64) {
        // stage: wave w stages chunks s = w*4 .. w*4+3 of both tiles
#pragma unroll
        for (int ss = 0; ss < 4; ++ss) {
            const int s  = w * 4 + ss;
            const int mg = s >> 1, ks = s & 1;
            const int row = mg * 16 + r15;
            const int col = k0 + ks * 32 + quad * 8;
            gload_lds16(A + (size_t)(m0 + row) * K + col, &Al[s * 512]);
            gload_lds16(W + (size_t)(n0 + row) * K + col, &Wl[s * 512]);
        }
        __syncthreads();

        short8 af[2][4], bf[2][4];
#pragma unroll
        for (int ks = 0; ks < 2; ++ks) {
#pragma unroll
            for (int mt = 0; mt < 4; ++mt)
                af[ks][mt] = *(const short8*)&Al[(((wm * 4 + mt) * 2 + ks) * 64 + lane) * 8];
#pragma unroll
            for (int nt = 0; nt < 4; ++nt)
                bf[ks][nt] = *(const short8*)&Wl[(((wn * 4 + nt) * 2 + ks) * 64 + lane) * 8];
        }
#pragma unroll
        for (int ks = 0; ks < 2; ++ks)
#pragma unroll
            for (int mt = 0; mt < 4; ++mt)
#pragma unroll
                for (int nt = 0; nt < 4; ++nt)
                    acc[mt][nt] = mfma16(af[ks][mt], bf[ks][nt], acc[mt][nt]);
        __syncthreads();
    }

    // epilogue (C-layout: row = quad*4+i, col = r15)
#pragma unroll
    for (int mt = 0; mt < 4; ++mt)
#pragma unroll
        for (int nt = 0; nt < 4; ++nt)
#pragma unroll
            for (int i = 0; i < 4; ++i) {
                const int m = m0 + wm * 64 + mt * 16 + quad * 4 + i;
                const int n = n0 + wn * 64 + nt * 16 + r15;
                const float v = acc[mt][nt][i];
                if (smode == 0) {
                    const int b = m >> 11, t = m & (T_ - 1);
                    const int h = n >> 7, dk = n & (DK_ - 1);
                    ((ushort_t*)C)[(((size_t)(b * H_ + h)) * T_ + t) * DK_ + dk] = f2bf(v);
                } else if (smode == 1) {
                    const int h = n >> 7, dk = n & (DK_ - 1);
                    ((ushort_t*)C)[((size_t)h * PS_ + m) * DK_ + dk] = f2bf(v);
                } else if (smode == 2) {
                    const int b = m >> 11, t = m & (T_ - 1);
                    const int h = n >> 7, dk = n & (DK_ - 1);
                    ((ushort_t*)C)[((size_t)(b * H_ + h) * DK_ + dk) * T_ + t] = f2bf(v);
                } else if (smode == 3) {
                    ((ushort_t*)C)[(size_t)m * N + n] = f2bf(v);
                } else {
                    ((float*)C)[(size_t)m * N + n] = v;
                }
            }
}

// ---------------------------------------------------------------------------
// MFMA flash attention, rel-shift folded:
//   score[q,k] = ((q+u)·K[k] + (q+v)·P[k-q+T-1]) / sqrt(DK)
// 4 waves x 16 q-rows, K-chunk 64; K (64x128), V^T (128x64), P band (128
// rows) in LDS in FRAGMENT ORDER (all MFMA ds_read_b128 = base+lane*16).
// Round-6 changes vs the verified round-2 (296us) kernel:
//  * REG-STAGED PREFETCH (T14) with the verified two-barrier skeleton:
//      write regs(n)->LDS; sync; issue global->reg(n+1); compute(n); sync
//    The end-of-iter barrier's implicit vmcnt(0) now drains loads that are
//    a full compute phase old (r2 drained freshly-issued DMA every iter).
//    Round-1's version of this FAILED because it lacked the end-of-iter
//    barrier (compute(n) raced next iter's LDS writes); the two-barrier
//    form has no such window. All global/LDS address expressions are
//    byte-identical to r2's verified staging.
//  * XCD-aware bijective swizzle (1024 blocks = 8 XCD x 128): each XCD gets
//    4 consecutive bh values (K/V/P working set ~8MB vs ~32MB scattered).
// LDS unchanged: 16+16+32+8 = 72KB -> 2 blocks/CU. VGPR grows by the 64
// staging regs (cap 256 at 2 waves/EU -> still LDS-bound occupancy).
// ---------------------------------------------------------------------------
__global__ __launch_bounds__(256, 2) void attn_mfma(
    const ushort_t* __restrict__ qg,
    const ushort_t* __restrict__ kgl,
    const ushort_t* __restrict__ vt,   // [B,H,DK,T]
    const ushort_t* __restrict__ pg,   // [H,PS_,DK]
    const ushort_t* __restrict__ ubb,  // bf16 [H,DK]
    const ushort_t* __restrict__ vbb,
    ushort_t* __restrict__ ao)         // [B,T,D]
{
    __shared__ ushort_t K_lds[16 * 512];   // chunks (gk,ks) = gk*4+ks
    __shared__ ushort_t V_lds[16 * 512];   // chunks (og,ks2) = og*2+ks2
    __shared__ ushort_t P_lds[32 * 512];   // chunks (gb,ks) = gb*4+ks
    __shared__ __align__(16) ushort_t pr_lds[4][1024];  // per-wave A-frag tile

    const int tid  = threadIdx.x;
    const int w    = tid >> 6;
    const int lane = tid & 63;
    const int r15  = lane & 15;
    const int quad = lane >> 4;

    // XCD-aware bijective remap: 1024 blocks = 8 XCDs x 128. HW block i goes
    // to XCD i%8; XCD k thus gets swz ids k*128..k*128+127 = bh 4k..4k+3.
    const int lin  = (int)(blockIdx.y * 32 + blockIdx.x);
    const int swz  = (lin & 7) * 128 + (lin >> 3);
    const int bh   = swz >> 5;
    const int h    = bh & (H_ - 1);
    const int b    = bh >> 3;
    const int q0b  = (swz & 31) * 64;
    const int q0w  = q0b + w * 16;

    // Q fragments (A-layout) with u/v biases folded
    short8 quA[4], qvA[4];
    {
        const ushort_t* qrow = qg + ((size_t)bh * T_ + q0w + r15) * DK_;
#pragma unroll
        for (int ks = 0; ks < 4; ++ks) {
            const int dk0 = ks * 32 + quad * 8;
            uint4 q4 = *(const uint4*)(qrow + dk0);
            uint4 u4 = *(const uint4*)(ubb + (size_t)h * DK_ + dk0);
            uint4 v4 = *(const uint4*)(vbb + (size_t)h * DK_ + dk0);
            const ushort_t* qs = (const ushort_t*)&q4;
            const ushort_t* us = (const ushort_t*)&u4;
            const ushort_t* vs = (const ushort_t*)&v4;
#pragma unroll
            for (int j = 0; j < 8; ++j) {
                const float qf = bf2f(qs[j]);
                quA[ks][j] = (short)f2bf(qf + bf2f(us[j]));
                qvA[ks][j] = (short)f2bf(qf + bf2f(vs[j]));
            }
        }
    }

    // rel-shift gather lane sources (wave-static per i)
    int src[4], hi[4];
#pragma unroll
    for (int i = 0; i < 4; ++i) {
        const int c = r15 + 15 - quad * 4 - i;   // in [0,30]
        src[i] = quad * 16 + (c & 15);
        hi[i]  = c >> 4;                          // 0 or 1
    }

    // ---- reg-staging: global->reg issue (addresses identical to r2) ----
    uint4 sK[4], sV[4], sP[8];
    auto issue = [&](int kc0) {
        const int pbb = kc0 - q0b + 1984;   // band base (>=0, +127 <= 4095)
#pragma unroll
        for (int ss = 0; ss < 4; ++ss) {
            sK[ss] = *(const uint4*)(kgl +
                ((size_t)bh * T_ + kc0 + w * 16 + r15) * DK_ + ss * 32 + quad * 8);
            const int cv = w * 4 + ss;
            const int og = cv >> 1, ks2 = cv & 1;
            sV[ss] = *(const uint4*)(vt +
                ((size_t)(bh * DK_ + og * 16 + r15)) * T_ + kc0 + ks2 * 32 + quad * 8);
        }
#pragma unroll
        for (int ss = 0; ss < 8; ++ss) {
            const int cp = w * 8 + ss;
            const int gb = cp >> 2, ks = cp & 3;
            sP[ss] = *(const uint4*)(pg +
                ((size_t)h * PS_ + pbb + gb * 16 + r15) * DK_ + ks * 32 + quad * 8);
        }
    };

    floatx4 o[8];
    const floatx4 z4 = {0.f, 0.f, 0.f, 0.f};
#pragma unroll
    for (int g = 0; g < 8; ++g) o[g] = z4;
    floatx4 lacc = z4;                 // row sums (C-layout, same rows as o)
    float mrun[4];
#pragma unroll
    for (int i = 0; i < 4; ++i) mrun[i] = -1e30f;

    short8 ones8;
#pragma unroll
    for (int j = 0; j < 8; ++j) ones8[j] = (short)0x3F80;   // bf16 1.0

    const float scale = 0.08838834764831845f;  // 1/sqrt(128)

    issue(0);
    const int NT = T_ / 64;
    for (int n = 0; n < NT; ++n) {
        // ---- write chunk n regs -> LDS (compiler waits vmcnt per reg; the
        //      loads are a full compute phase old except at n=0) ----
#pragma unroll
        for (int ss = 0; ss < 4; ++ss) {
            *(uint4*)&K_lds[((w * 4 + ss) * 64 + lane) * 8] = sK[ss];
            *(uint4*)&V_lds[((w * 4 + ss) * 64 + lane) * 8] = sV[ss];
        }
#pragma unroll
        for (int ss = 0; ss < 8; ++ss)
            *(uint4*)&P_lds[((w * 8 + ss) * 64 + lane) * 8] = sP[ss];
        __syncthreads();   // writes visible to all waves; nothing in vm queue

        // ---- prefetch chunk n+1 into regs; lands during compute ----
        if (n + 1 < NT) issue((n + 1) * 64);

        // ---- AC = Qu x K^T ----
        floatx4 ac[4];
#pragma unroll
        for (int g = 0; g < 4; ++g) {
            ac[g] = z4;
#pragma unroll
            for (int ks = 0; ks < 4; ++ks)
                ac[g] = mfma16(quA[ks],
                               *(const short8*)&K_lds[((g * 4 + ks) * 64 + lane) * 8],
                               ac[g]);
        }
        // ---- BD band = Qv x P_band^T (wave window = groups (3-w)..(3-w)+4) ----
        floatx4 bd[5];
#pragma unroll
        for (int g = 0; g < 5; ++g) {
            bd[g] = z4;
            const int gb = (3 - w) + g;
#pragma unroll
            for (int ks = 0; ks < 4; ++ks)
                bd[g] = mfma16(qvA[ks],
                               *(const short8*)&P_lds[((gb * 4 + ks) * 64 + lane) * 8],
                               bd[g]);
        }

        // ---- scores: shift-gather via shfl; chunk max via DPP (VALU) ----
        float pr[4][4];
        float mc[4];
#pragma unroll
        for (int i = 0; i < 4; ++i) {
            float mm = -1e30f;
#pragma unroll
            for (int g = 0; g < 4; ++g) {
                const float lo = __shfl(bd[g][i],     src[i], 64);
                const float hh = __shfl(bd[g + 1][i], src[i], 64);
                const float s  = (ac[g][i] + (hi[i] ? hh : lo)) * scale;
                pr[g][i] = s;
                mm = fmaxf(mm, s);
            }
            mc[i] = rowmax16(mm);
        }
        // conditional rescale: only when some row's max grew (skip is exact)
        const bool nd = (mc[0] > mrun[0]) | (mc[1] > mrun[1]) |
                        (mc[2] > mrun[2]) | (mc[3] > mrun[3]);
        if (__any(nd)) {
            float alpha[4];
#pragma unroll
            for (int i = 0; i < 4; ++i) {
                const float mn = fmaxf(mrun[i], mc[i]);
                alpha[i] = __expf(mrun[i] - mn);
                mrun[i] = mn;
            }
#pragma unroll
            for (int g = 0; g < 8; ++g)
#pragma unroll
                for (int i = 0; i < 4; ++i) o[g][i] *= alpha[i];
#pragma unroll
            for (int i = 0; i < 4; ++i) lacc[i] *= alpha[i];
        }
#pragma unroll
        for (int g = 0; g < 4; ++g)
#pragma unroll
            for (int i = 0; i < 4; ++i)
                pr[g][i] = __expf(pr[g][i] - mrun[i]);

        // ---- probs C->A via per-wave fragment-ordered LDS ----
        // element (row=quad*4+i, col=g*16+r15): unit (ks2=g>>1, kq=(g&1)*2+(r15>>3))
#pragma unroll
        for (int g = 0; g < 4; ++g) {
            const int unit = (g >> 1) * 4 + (g & 1) * 2 + (r15 >> 3);
#pragma unroll
            for (int i = 0; i < 4; ++i)
                pr_lds[w][(unit * 16 + quad * 4 + i) * 8 + (r15 & 7)] = f2bf(pr[g][i]);
        }
        // wave-private region: compiler lgkmcnt ordering suffices (no barrier)
        short8 pa[2];
#pragma unroll
        for (int ks2 = 0; ks2 < 2; ++ks2)
            pa[ks2] = *(const short8*)&pr_lds[w][(ks2 * 64 + lane) * 8];

        // ---- PV: probs (A-layout) x V^T; row-sum rides along as mfma-ones ----
#pragma unroll
        for (int og = 0; og < 8; ++og)
#pragma unroll
            for (int ks2 = 0; ks2 < 2; ++ks2)
                o[og] = mfma16(pa[ks2],
                               *(const short8*)&V_lds[((og * 2 + ks2) * 64 + lane) * 8],
                               o[og]);
        lacc = mfma16(pa[0], ones8, lacc);
        lacc = mfma16(pa[1], ones8, lacc);

        // end-of-iter barrier: all waves done READING K/V/P (so next iter's
        // writes can't race), and chunk n+1's loads drain here after having
        // had the whole compute phase to land.
        __syncthreads();
    }

    // ---- epilogue ----
    float inv[4];
#pragma unroll
    for (int i = 0; i < 4; ++i) inv[i] = 1.0f / lacc[i];
#pragma unroll
    for (int og = 0; og < 8; ++og)
#pragma unroll
        for (int i = 0; i < 4; ++i) {
            const size_t idx =
                ((size_t)(b * T_ + q0w + quad * 4 + i)) * D_ + h * DK_ + og * 16 + r15;
            ao[idx] = f2bf(o[og][i] * inv[i]);
        }
}

// ---------------------------------------------------------------------------
extern "C" void kernel_launch(void* const* d_in, const int* in_sizes, int n_in,
                              void* d_out, int out_size, void* d_ws, size_t ws_size,
                              hipStream_t stream) {
    const void* x  = d_in[0];
    const void* pe = d_in[1];
    const void* Wq = d_in[2];
    const void* Wk = d_in[3];
    const void* Wv = d_in[4];
    const void* Wo = d_in[5];
    const void* Wp = d_in[6];
    const void* ub = d_in[7];
    const void* vb = d_in[8];

    int* flag = (int*)d_ws;
    ushort_t* arena = (ushort_t*)d_ws + 16;   // +32 B
    ushort_t* xb   = arena;                    // 8,388,608   (reused as ao_ws)
    ushort_t* peb  = arena + 8388608;          // 4,194,304 (4096 rows, last = junk)
    ushort_t* wqb  = arena + 12582912;
    ushort_t* wkb  = wqb + 1048576;
    ushort_t* wvb  = wkb + 1048576;
    ushort_t* wob  = wvb + 1048576;
    ushort_t* wpb  = wob + 1048576;
    ushort_t* ubb  = arena + 17825792;
    ushort_t* vbb  = ubb + 1024;
    ushort_t* q_ws  = arena + 17827840;
    ushort_t* k_ws  = q_ws + 8388608;
    ushort_t* vt_ws = k_ws + 8388608;          // [B,H,DK,T]
    ushort_t* p_ws  = vt_ws + 8388608;         // [H,PS_,DK]
    ushort_t* ao_ws = xb;                      // x dead after q/k/v GEMMs

    detect_kernel<<<1, 64, 0, stream>>>((const ushort_t*)x, flag);

    const int cvb = CV_TOT / 4 / 256;          // 17409 exact
    convert_kernel<0><<<cvb, 256, 0, stream>>>(flag, x, pe, Wq, Wk, Wv, Wo, Wp, ub, vb, arena);
    convert_kernel<1><<<cvb, 256, 0, stream>>>(flag, x, pe, Wq, Wk, Wv, Wo, Wp, ub, vb, arena);

    const dim3 gX(8, 64);   // N/128, M/128 for M=8192
    const dim3 gP(8, 32);   // M=4096 (padded)
    gemm_mfma<<<gX, 256, 0, stream>>>(flag, xb,  wqb, q_ws, 0);
    gemm_mfma<<<gX, 256, 0, stream>>>(flag, xb,  wkb, k_ws, 0);
    gemm_mfma<<<gX, 256, 0, stream>>>(flag, xb,  wvb, vt_ws, 2);
    gemm_mfma<<<gP, 256, 0, stream>>>(flag, peb, wpb, p_ws, 1);

    attn_mfma<<<dim3(T_ / 64, B_ * H_), 256, 0, stream>>>(
        q_ws, k_ws, vt_ws, p_ws, ubb, vbb, ao_ws);

    gemm_mfma<<<gX, 256, 0, stream>>>(flag, ao_ws, wob, d_out, 3);
    gemm_mfma<<<gX, 256, 0, stream>>>(flag, ao_ws, wob, d_out, 4);
}

// Round 7
// 585.640 us; speedup vs baseline: 1.7780x; 1.7780x over previous
//
#include <hip/hip_runtime.h>
#include <cstdint>
#include <math.h>

// Problem constants
#define B_   4
#define T_   2048
#define D_   1024
#define H_   8
#define DK_  128
#define P_   4095   // 2T-1
#define PS_  4096   // padded P rows per head (row 4095 = finite junk, never consumed)

typedef unsigned short ushort_t;
typedef __attribute__((ext_vector_type(8))) short short8;
typedef __attribute__((ext_vector_type(4))) float floatx4;

__device__ inline float bf2f(ushort_t s) {
    return __uint_as_float(((unsigned int)s) << 16);
}
__device__ inline ushort_t f2bf(float f) {
    unsigned int u = __float_as_uint(f);
    u += 0x7fffu + ((u >> 16) & 1u);   // round-to-nearest-even
    return (ushort_t)(u >> 16);
}

__device__ inline floatx4 mfma16(short8 a, short8 b, floatx4 c) {
    return __builtin_amdgcn_mfma_f32_16x16x32_bf16(a, b, c, 0, 0, 0);
}

// async global->LDS, 16B per lane; LDS dest = wave-uniform base + lane*16
__device__ inline void gload_lds16(const ushort_t* g, ushort_t* l) {
    __builtin_amdgcn_global_load_lds(
        (const __attribute__((address_space(1))) unsigned int*)g,
        (__attribute__((address_space(3))) unsigned int*)l, 16, 0, 0);
}

// 16-lane (DPP-row) max reduction on the VALU pipe (keeps LDS pipe free).
// ror8 -> ror4 -> quad_perm xor2 -> quad_perm xor1 = full 16-lane all-reduce.
__device__ inline float rowmax16(float x) {
    int t;
    t = __builtin_amdgcn_update_dpp(0, __float_as_int(x), 0x128, 0xf, 0xf, true); // row_ror:8
    x = fmaxf(x, __int_as_float(t));
    t = __builtin_amdgcn_update_dpp(0, __float_as_int(x), 0x124, 0xf, 0xf, true); // row_ror:4
    x = fmaxf(x, __int_as_float(t));
    t = __builtin_amdgcn_update_dpp(0, __float_as_int(x), 0x4E, 0xf, 0xf, true);  // quad_perm xor2
    x = fmaxf(x, __int_as_float(t));
    t = __builtin_amdgcn_update_dpp(0, __float_as_int(x), 0xB1, 0xf, 0xf, true);  // quad_perm xor1
    x = fmaxf(x, __int_as_float(t));
    return x;
}

// dtype detector: flag 0 = bf16 inputs, 1 = fp32 inputs.
__global__ void detect_kernel(const ushort_t* x, int* flag) {
    if (blockIdx.x == 0 && threadIdx.x == 0) {
        int m = 0;
        for (int i = 0; i < 64; ++i) {
            float v = bf2f(x[2 * i]);
            float a = fabsf(v);
            if (!(a == 0.0f || (a > 1e-20f && a < 1e10f))) m = 1;
        }
        flag[0] = m;
    }
}

// ---------------------------------------------------------------------------
// Conversion: all external tensors -> contiguous bf16 arena (see r4 offsets).
// ---------------------------------------------------------------------------
#define CV_TOT 17826816
template <int MODE>
__global__ __launch_bounds__(256) void convert_kernel(
    const int* __restrict__ flag,
    const void* __restrict__ x, const void* __restrict__ pe,
    const void* __restrict__ wq, const void* __restrict__ wk,
    const void* __restrict__ wv, const void* __restrict__ wo,
    const void* __restrict__ wp, const void* __restrict__ ub,
    const void* __restrict__ vb, ushort_t* __restrict__ dst)
{
    if (flag[0] != MODE) return;
    const size_t i = ((size_t)blockIdx.x * 256 + threadIdx.x) * 4;
    if (i >= CV_TOT) return;
    const void* s; size_t off;
    if (i < 8388608)       { s = x;  off = i; }
    else if (i < 12581888) { s = pe; off = i - 8388608; }
    else if (i < 13630464) { s = wq; off = i - 12581888; }
    else if (i < 14679040) { s = wk; off = i - 13630464; }
    else if (i < 15727616) { s = wv; off = i - 14679040; }
    else if (i < 16776192) { s = wo; off = i - 15727616; }
    else if (i < 17824768) { s = wp; off = i - 16776192; }
    else if (i < 17825792) { s = ub; off = i - 17824768; }
    else                   { s = vb; off = i - 17825792; }
    const size_t d = i + (i >= 12581888 ? 1024 : 0);
    if (MODE == 0) {
        *(uint2*)(dst + d) = *(const uint2*)((const ushort_t*)s + off);
    } else {
        float4 f = *(const float4*)((const float*)s + off);
        uint2 o;
        o.x = (unsigned)f2bf(f.x) | ((unsigned)f2bf(f.y) << 16);
        o.y = (unsigned)f2bf(f.z) | ((unsigned)f2bf(f.w) << 16);
        *(uint2*)(dst + d) = o;
    }
}

// ---------------------------------------------------------------------------
// MFMA GEMM: C[m,n] = sum_k A[m,k]*W[n,k], A[M,1024], W[N,1024] bf16.
// 128x128 tile, BK=64, 4 waves 2x2 (each 64x64 = 4x4 mfma tiles).
// LDS in FRAGMENT ORDER (see r2 notes); all ds_read_b128 conflict-free.
// smode: 0 -> [B,H,T,DK]; 1 -> [H,PS,DK]; 2 -> [B,H,DK,T];
//        3 -> row-major bf16 (iff flag==0); 4 -> row-major fp32 (iff flag==1)
//        5 -> FUSED q|k|v epilogue: W is the contiguous [3072,1024] wq|wk|wv
//             stack, C is the contiguous q_ws|k_ws|vt_ws arena region; col
//             block n>>10 selects {q: smode0 layout, k: smode0 +8M elems,
//             v: smode2 +16M elems}.
// ---------------------------------------------------------------------------
__global__ __launch_bounds__(256, 3) void gemm_mfma(
    const int* __restrict__ flag,
    const ushort_t* __restrict__ A, const ushort_t* __restrict__ W,
    void* __restrict__ C, int smode)
{
    if (smode == 3 && flag[0] != 0) return;
    if (smode == 4 && flag[0] != 1) return;
    const int K = 1024, N = 1024;

    __shared__ ushort_t Al[16 * 512];   // 16 chunks x 512 ushorts (16KB)
    __shared__ ushort_t Wl[16 * 512];

    const int tid  = threadIdx.x;
    const int w    = tid >> 6, lane = tid & 63;
    const int r15  = lane & 15, quad = lane >> 4;
    const int wm   = w >> 1, wn = w & 1;
    const int m0   = blockIdx.y * 128, n0 = blockIdx.x * 128;

    floatx4 acc[4][4];
    const floatx4 z4 = {0.f, 0.f, 0.f, 0.f};
#pragma unroll
    for (int mt = 0; mt < 4; ++mt)
#pragma unroll
        for (int nt = 0; nt < 4; ++nt) acc[mt][nt] = z4;

    for (int k0 = 0; k0 < K; k0 += 64) {
        // stage: wave w stages chunks s = w*4 .. w*4+3 of both tiles
#pragma unroll
        for (int ss = 0; ss < 4; ++ss) {
            const int s  = w * 4 + ss;
            const int mg = s >> 1, ks = s & 1;
            const int row = mg * 16 + r15;
            const int col = k0 + ks * 32 + quad * 8;
            gload_lds16(A + (size_t)(m0 + row) * K + col, &Al[s * 512]);
            gload_lds16(W + (size_t)(n0 + row) * K + col, &Wl[s * 512]);
        }
        __syncthreads();

        short8 af[2][4], bf[2][4];
#pragma unroll
        for (int ks = 0; ks < 2; ++ks) {
#pragma unroll
            for (int mt = 0; mt < 4; ++mt)
                af[ks][mt] = *(const short8*)&Al[(((wm * 4 + mt) * 2 + ks) * 64 + lane) * 8];
#pragma unroll
            for (int nt = 0; nt < 4; ++nt)
                bf[ks][nt] = *(const short8*)&Wl[(((wn * 4 + nt) * 2 + ks) * 64 + lane) * 8];
        }
#pragma unroll
        for (int ks = 0; ks < 2; ++ks)
#pragma unroll
            for (int mt = 0; mt < 4; ++mt)
#pragma unroll
                for (int nt = 0; nt < 4; ++nt)
                    acc[mt][nt] = mfma16(af[ks][mt], bf[ks][nt], acc[mt][nt]);
        __syncthreads();
    }

    // epilogue (C-layout: row = quad*4+i, col = r15)
#pragma unroll
    for (int mt = 0; mt < 4; ++mt)
#pragma unroll
        for (int nt = 0; nt < 4; ++nt)
#pragma unroll
            for (int i = 0; i < 4; ++i) {
                const int m = m0 + wm * 64 + mt * 16 + quad * 4 + i;
                const int n = n0 + wn * 64 + nt * 16 + r15;
                const float v = acc[mt][nt][i];
                if (smode == 0) {
                    const int b = m >> 11, t = m & (T_ - 1);
                    const int h = n >> 7, dk = n & (DK_ - 1);
                    ((ushort_t*)C)[(((size_t)(b * H_ + h)) * T_ + t) * DK_ + dk] = f2bf(v);
                } else if (smode == 1) {
                    const int h = n >> 7, dk = n & (DK_ - 1);
                    ((ushort_t*)C)[((size_t)h * PS_ + m) * DK_ + dk] = f2bf(v);
                } else if (smode == 2) {
                    const int b = m >> 11, t = m & (T_ - 1);
                    const int h = n >> 7, dk = n & (DK_ - 1);
                    ((ushort_t*)C)[((size_t)(b * H_ + h) * DK_ + dk) * T_ + t] = f2bf(v);
                } else if (smode == 3) {
                    ((ushort_t*)C)[(size_t)m * N + n] = f2bf(v);
                } else if (smode == 4) {
                    ((float*)C)[(size_t)m * N + n] = v;
                } else {   // smode 5: fused q|k|v
                    const int b = m >> 11, t = m & (T_ - 1);
                    const int nn = n & 1023;
                    const int h = nn >> 7, dk = nn & (DK_ - 1);
                    const int wsel = n >> 10;          // 0=q, 1=k, 2=v
                    size_t idx;
                    if (wsel == 2)
                        idx = (size_t)16777216 + ((size_t)(b * H_ + h) * DK_ + dk) * T_ + t;
                    else
                        idx = (size_t)wsel * 8388608 +
                              (((size_t)(b * H_ + h)) * T_ + t) * DK_ + dk;
                    ((ushort_t*)C)[idx] = f2bf(v);
                }
            }
}

// ---------------------------------------------------------------------------
// MFMA flash attention, rel-shift folded:
//   score[q,k] = ((q+u)·K[k] + (q+v)·P[k-q+T-1]) / sqrt(DK)
// 4 waves x 16 q-rows, K-chunk 64. K (64x128), V^T (128x64) and the block's
// P band union (exactly 128 rows) staged in LDS via gload_lds16 in FRAGMENT
// ORDER (all MFMA ds_read_b128 are base+lane*16, conflict-free).
// This is the VERIFIED round-2 (296us) kernel body, byte-identical except:
//  * XCD-aware bijective block remap (hardware-validated in r6): 1024 blocks
//    = 8 XCDs x 128; each XCD's 128 blocks span only 4 consecutive bh ->
//    K/V/P working set per XCD ~8MB instead of ~32MB (r4/r6: FETCH -11%).
// Schedule/staging NOT touched: r3 (1-block dbuf), r4 (global-P), r5
// (128-row tile), r6 (reg-staging -> scratch spill, WRITE_SIZE 2GB) all
// regressed; this structure is the measured local optimum.
// LDS: 16+16+32+8 = 72KB -> 2 blocks/CU.
// ---------------------------------------------------------------------------
__global__ __launch_bounds__(256, 2) void attn_mfma(
    const ushort_t* __restrict__ qg,
    const ushort_t* __restrict__ kgl,
    const ushort_t* __restrict__ vt,   // [B,H,DK,T]
    const ushort_t* __restrict__ pg,   // [H,PS_,DK]
    const ushort_t* __restrict__ ubb,  // bf16 [H,DK]
    const ushort_t* __restrict__ vbb,
    ushort_t* __restrict__ ao)         // [B,T,D]
{
    __shared__ ushort_t K_lds[16 * 512];   // chunks (gk,ks) = gk*4+ks
    __shared__ ushort_t V_lds[16 * 512];   // chunks (og,ks2) = og*2+ks2
    __shared__ ushort_t P_lds[32 * 512];   // chunks (gb,ks) = gb*4+ks
    __shared__ __align__(16) ushort_t pr_lds[4][1024];  // per-wave A-frag tile

    const int tid  = threadIdx.x;
    const int w    = tid >> 6;
    const int lane = tid & 63;
    const int r15  = lane & 15;
    const int quad = lane >> 4;

    // XCD-aware bijective remap (1024 = 8 x 128; HW block i -> XCD i%8, so
    // XCD k serves swz ids k*128..k*128+127 = bh 4k..4k+3).
    const int lin  = (int)(blockIdx.y * 32 + blockIdx.x);
    const int swz  = (lin & 7) * 128 + (lin >> 3);
    const int bh   = swz >> 5;
    const int h    = bh & (H_ - 1);
    const int b    = bh >> 3;
    const int q0b  = (swz & 31) * 64;
    const int q0w  = q0b + w * 16;

    // Q fragments (A-layout) with u/v biases folded
    short8 quA[4], qvA[4];
    {
        const ushort_t* qrow = qg + ((size_t)bh * T_ + q0w + r15) * DK_;
#pragma unroll
        for (int ks = 0; ks < 4; ++ks) {
            const int dk0 = ks * 32 + quad * 8;
            uint4 q4 = *(const uint4*)(qrow + dk0);
            uint4 u4 = *(const uint4*)(ubb + (size_t)h * DK_ + dk0);
            uint4 v4 = *(const uint4*)(vbb + (size_t)h * DK_ + dk0);
            const ushort_t* qs = (const ushort_t*)&q4;
            const ushort_t* us = (const ushort_t*)&u4;
            const ushort_t* vs = (const ushort_t*)&v4;
#pragma unroll
            for (int j = 0; j < 8; ++j) {
                const float qf = bf2f(qs[j]);
                quA[ks][j] = (short)f2bf(qf + bf2f(us[j]));
                qvA[ks][j] = (short)f2bf(qf + bf2f(vs[j]));
            }
        }
    }

    // rel-shift gather lane sources (wave-static per i)
    int src[4], hi[4];
#pragma unroll
    for (int i = 0; i < 4; ++i) {
        const int c = r15 + 15 - quad * 4 - i;   // in [0,30]
        src[i] = quad * 16 + (c & 15);
        hi[i]  = c >> 4;                          // 0 or 1
    }

    floatx4 o[8];
    const floatx4 z4 = {0.f, 0.f, 0.f, 0.f};
#pragma unroll
    for (int g = 0; g < 8; ++g) o[g] = z4;
    floatx4 lacc = z4;                 // row sums (C-layout, same rows as o)
    float mrun[4];
#pragma unroll
    for (int i = 0; i < 4; ++i) mrun[i] = -1e30f;

    short8 ones8;
#pragma unroll
    for (int j = 0; j < 8; ++j) ones8[j] = (short)0x3F80;   // bf16 1.0

    const float scale = 0.08838834764831845f;  // 1/sqrt(128)

    for (int kc0 = 0; kc0 < T_; kc0 += 64) {
        const int pbb = kc0 - q0b + 1984;   // block band base (>=0, +127 <= 4095)

        // ---- stage K (4 chunks/wave), V^T (4), P band (8) ----
#pragma unroll
        for (int ss = 0; ss < 4; ++ss) {
            const int ck = w * 4 + ss;            // (gk,ks) = (w, ss)
            gload_lds16(kgl + ((size_t)bh * T_ + kc0 + w * 16 + r15) * DK_ + ss * 32 + quad * 8,
                        &K_lds[ck * 512]);
            const int cv = w * 4 + ss;            // (og,ks2) = (cv>>1, cv&1)
            const int og = cv >> 1, ks2 = cv & 1;
            gload_lds16(vt + ((size_t)(bh * DK_ + og * 16 + r15)) * T_ + kc0 + ks2 * 32 + quad * 8,
                        &V_lds[cv * 512]);
        }
#pragma unroll
        for (int ss = 0; ss < 8; ++ss) {
            const int cp = w * 8 + ss;            // (gb,ks) = (cp>>2, cp&3)
            const int gb = cp >> 2, ks = cp & 3;
            gload_lds16(pg + ((size_t)h * PS_ + pbb + gb * 16 + r15) * DK_ + ks * 32 + quad * 8,
                        &P_lds[cp * 512]);
        }
        __syncthreads();

        // ---- AC = Qu x K^T ----
        floatx4 ac[4];
#pragma unroll
        for (int g = 0; g < 4; ++g) {
            ac[g] = z4;
#pragma unroll
            for (int ks = 0; ks < 4; ++ks)
                ac[g] = mfma16(quA[ks],
                               *(const short8*)&K_lds[((g * 4 + ks) * 64 + lane) * 8],
                               ac[g]);
        }
        // ---- BD band = Qv x P_band^T (wave window = groups (3-w)..(3-w)+4) ----
        floatx4 bd[5];
#pragma unroll
        for (int g = 0; g < 5; ++g) {
            bd[g] = z4;
            const int gb = (3 - w) + g;
#pragma unroll
            for (int ks = 0; ks < 4; ++ks)
                bd[g] = mfma16(qvA[ks],
                               *(const short8*)&P_lds[((gb * 4 + ks) * 64 + lane) * 8],
                               bd[g]);
        }

        // ---- scores: shift-gather via shfl; chunk max via DPP (VALU) ----
        float pr[4][4];
        float mc[4];
#pragma unroll
        for (int i = 0; i < 4; ++i) {
            float mm = -1e30f;
#pragma unroll
            for (int g = 0; g < 4; ++g) {
                const float lo = __shfl(bd[g][i],     src[i], 64);
                const float hh = __shfl(bd[g + 1][i], src[i], 64);
                const float s  = (ac[g][i] + (hi[i] ? hh : lo)) * scale;
                pr[g][i] = s;
                mm = fmaxf(mm, s);
            }
            mc[i] = rowmax16(mm);
        }
        // conditional rescale: only when some row's max grew (skip is exact:
        // otherwise mn==mrun and alpha==1 for every row)
        const bool nd = (mc[0] > mrun[0]) | (mc[1] > mrun[1]) |
                        (mc[2] > mrun[2]) | (mc[3] > mrun[3]);
        if (__any(nd)) {
            float alpha[4];
#pragma unroll
            for (int i = 0; i < 4; ++i) {
                const float mn = fmaxf(mrun[i], mc[i]);
                alpha[i] = __expf(mrun[i] - mn);
                mrun[i] = mn;
            }
#pragma unroll
            for (int g = 0; g < 8; ++g)
#pragma unroll
                for (int i = 0; i < 4; ++i) o[g][i] *= alpha[i];
#pragma unroll
            for (int i = 0; i < 4; ++i) lacc[i] *= alpha[i];
        }
#pragma unroll
        for (int g = 0; g < 4; ++g)
#pragma unroll
            for (int i = 0; i < 4; ++i)
                pr[g][i] = __expf(pr[g][i] - mrun[i]);

        // ---- probs C->A via per-wave fragment-ordered LDS ----
        // element (row=quad*4+i, col=g*16+r15): unit (ks2=g>>1, kq=(g&1)*2+(r15>>3))
#pragma unroll
        for (int g = 0; g < 4; ++g) {
            const int unit = (g >> 1) * 4 + (g & 1) * 2 + (r15 >> 3);
#pragma unroll
            for (int i = 0; i < 4; ++i)
                pr_lds[w][(unit * 16 + quad * 4 + i) * 8 + (r15 & 7)] = f2bf(pr[g][i]);
        }
        // wave-private region: compiler lgkmcnt ordering suffices (no barrier)
        short8 pa[2];
#pragma unroll
        for (int ks2 = 0; ks2 < 2; ++ks2)
            pa[ks2] = *(const short8*)&pr_lds[w][(ks2 * 64 + lane) * 8];

        // ---- PV: probs (A-layout) x V^T; row-sum rides along as mfma-ones ----
#pragma unroll
        for (int og = 0; og < 8; ++og)
#pragma unroll
            for (int ks2 = 0; ks2 < 2; ++ks2)
                o[og] = mfma16(pa[ks2],
                               *(const short8*)&V_lds[((og * 2 + ks2) * 64 + lane) * 8],
                               o[og]);
        lacc = mfma16(pa[0], ones8, lacc);
        lacc = mfma16(pa[1], ones8, lacc);
        __syncthreads();   // all waves done with K/V/P before restage
    }

    // ---- epilogue ----
    float inv[4];
#pragma unroll
    for (int i = 0; i < 4; ++i) inv[i] = 1.0f / lacc[i];
#pragma unroll
    for (int og = 0; og < 8; ++og)
#pragma unroll
        for (int i = 0; i < 4; ++i) {
            const size_t idx =
                ((size_t)(b * T_ + q0w + quad * 4 + i)) * D_ + h * DK_ + og * 16 + r15;
            ao[idx] = f2bf(o[og][i] * inv[i]);
        }
}

// ---------------------------------------------------------------------------
extern "C" void kernel_launch(void* const* d_in, const int* in_sizes, int n_in,
                              void* d_out, int out_size, void* d_ws, size_t ws_size,
                              hipStream_t stream) {
    const void* x  = d_in[0];
    const void* pe = d_in[1];
    const void* Wq = d_in[2];
    const void* Wk = d_in[3];
    const void* Wv = d_in[4];
    const void* Wo = d_in[5];
    const void* Wp = d_in[6];
    const void* ub = d_in[7];
    const void* vb = d_in[8];

    int* flag = (int*)d_ws;
    ushort_t* arena = (ushort_t*)d_ws + 16;   // +32 B
    ushort_t* xb   = arena;                    // 8,388,608   (reused as ao_ws)
    ushort_t* peb  = arena + 8388608;          // 4,194,304 (4096 rows, last = junk)
    ushort_t* wqb  = arena + 12582912;         // wq|wk|wv contiguous [3072,1024]
    ushort_t* wkb  = wqb + 1048576;
    ushort_t* wvb  = wkb + 1048576;
    ushort_t* wob  = wvb + 1048576;
    ushort_t* wpb  = wob + 1048576;
    ushort_t* ubb  = arena + 17825792;
    ushort_t* vbb  = ubb + 1024;
    ushort_t* q_ws  = arena + 17827840;        // q_ws|k_ws|vt_ws contiguous
    ushort_t* k_ws  = q_ws + 8388608;
    ushort_t* vt_ws = k_ws + 8388608;          // [B,H,DK,T]
    ushort_t* p_ws  = vt_ws + 8388608;         // [H,PS_,DK]
    ushort_t* ao_ws = xb;                      // x dead after q/k/v GEMMs

    detect_kernel<<<1, 64, 0, stream>>>((const ushort_t*)x, flag);

    const int cvb = CV_TOT / 4 / 256;          // 17409 exact
    convert_kernel<0><<<cvb, 256, 0, stream>>>(flag, x, pe, Wq, Wk, Wv, Wo, Wp, ub, vb, arena);
    convert_kernel<1><<<cvb, 256, 0, stream>>>(flag, x, pe, Wq, Wk, Wv, Wo, Wp, ub, vb, arena);

    // FUSED q|k|v projection: M=8192, N=3072 (weights contiguous), one launch.
    gemm_mfma<<<dim3(24, 64), 256, 0, stream>>>(flag, xb, wqb, q_ws, 5);
    // P projection: M=4096 (padded), N=1024.
    gemm_mfma<<<dim3(8, 32), 256, 0, stream>>>(flag, peb, wpb, p_ws, 1);

    attn_mfma<<<dim3(T_ / 64, B_ * H_), 256, 0, stream>>>(
        q_ws, k_ws, vt_ws, p_ws, ubb, vbb, ao_ws);

    const dim3 gX(8, 64);   // N/128, M/128 for M=8192
    gemm_mfma<<<gX, 256, 0, stream>>>(flag, ao_ws, wob, d_out, 3);
    gemm_mfma<<<gX, 256, 0, stream>>>(flag, ao_ws, wob, d_out, 4);
}

// Round 8
// 555.530 us; speedup vs baseline: 1.8744x; 1.0542x over previous
//
#include <hip/hip_runtime.h>
#include <cstdint>
#include <math.h>

// Problem constants
#define B_   4
#define T_   2048
#define D_   1024
#define H_   8
#define DK_  128
#define P_   4095   // 2T-1
#define PS_  4096   // padded P rows per head (row 4095 = finite junk, never consumed)

typedef unsigned short ushort_t;
typedef __attribute__((ext_vector_type(8))) short short8;
typedef __attribute__((ext_vector_type(4))) float floatx4;

__device__ inline float bf2f(ushort_t s) {
    return __uint_as_float(((unsigned int)s) << 16);
}
__device__ inline ushort_t f2bf(float f) {
    unsigned int u = __float_as_uint(f);
    u += 0x7fffu + ((u >> 16) & 1u);   // round-to-nearest-even
    return (ushort_t)(u >> 16);
}

__device__ inline floatx4 mfma16(short8 a, short8 b, floatx4 c) {
    return __builtin_amdgcn_mfma_f32_16x16x32_bf16(a, b, c, 0, 0, 0);
}

// async global->LDS, 16B per lane; LDS dest = wave-uniform base + lane*16
__device__ inline void gload_lds16(const ushort_t* g, ushort_t* l) {
    __builtin_amdgcn_global_load_lds(
        (const __attribute__((address_space(1))) unsigned int*)g,
        (__attribute__((address_space(3))) unsigned int*)l, 16, 0, 0);
}

// 16-lane (DPP-row) max reduction on the VALU pipe (keeps LDS pipe free).
// ror8 -> ror4 -> quad_perm xor2 -> quad_perm xor1 = full 16-lane all-reduce.
__device__ inline float rowmax16(float x) {
    int t;
    t = __builtin_amdgcn_update_dpp(0, __float_as_int(x), 0x128, 0xf, 0xf, true); // row_ror:8
    x = fmaxf(x, __int_as_float(t));
    t = __builtin_amdgcn_update_dpp(0, __float_as_int(x), 0x124, 0xf, 0xf, true); // row_ror:4
    x = fmaxf(x, __int_as_float(t));
    t = __builtin_amdgcn_update_dpp(0, __float_as_int(x), 0x4E, 0xf, 0xf, true);  // quad_perm xor2
    x = fmaxf(x, __int_as_float(t));
    t = __builtin_amdgcn_update_dpp(0, __float_as_int(x), 0xB1, 0xf, 0xf, true);  // quad_perm xor1
    x = fmaxf(x, __int_as_float(t));
    return x;
}

// dtype detector: flag 0 = bf16 inputs, 1 = fp32 inputs.
__global__ void detect_kernel(const ushort_t* x, int* flag) {
    if (blockIdx.x == 0 && threadIdx.x == 0) {
        int m = 0;
        for (int i = 0; i < 64; ++i) {
            float v = bf2f(x[2 * i]);
            float a = fabsf(v);
            if (!(a == 0.0f || (a > 1e-20f && a < 1e10f))) m = 1;
        }
        flag[0] = m;
    }
}

// ---------------------------------------------------------------------------
// Conversion: all external tensors -> contiguous bf16 arena (r8: single
// launch, runtime flag branch instead of two templated launches).
// ---------------------------------------------------------------------------
#define CV_TOT 17826816
__global__ __launch_bounds__(256) void convert_kernel(
    const int* __restrict__ flag,
    const void* __restrict__ x, const void* __restrict__ pe,
    const void* __restrict__ wq, const void* __restrict__ wk,
    const void* __restrict__ wv, const void* __restrict__ wo,
    const void* __restrict__ wp, const void* __restrict__ ub,
    const void* __restrict__ vb, ushort_t* __restrict__ dst)
{
    const size_t i = ((size_t)blockIdx.x * 256 + threadIdx.x) * 4;
    if (i >= CV_TOT) return;
    const void* s; size_t off;
    if (i < 8388608)       { s = x;  off = i; }
    else if (i < 12581888) { s = pe; off = i - 8388608; }
    else if (i < 13630464) { s = wq; off = i - 12581888; }
    else if (i < 14679040) { s = wk; off = i - 13630464; }
    else if (i < 15727616) { s = wv; off = i - 14679040; }
    else if (i < 16776192) { s = wo; off = i - 15727616; }
    else if (i < 17824768) { s = wp; off = i - 16776192; }
    else if (i < 17825792) { s = ub; off = i - 17824768; }
    else                   { s = vb; off = i - 17825792; }
    const size_t d = i + (i >= 12581888 ? 1024 : 0);
    if (flag[0] == 0) {
        *(uint2*)(dst + d) = *(const uint2*)((const ushort_t*)s + off);
    } else {
        float4 f = *(const float4*)((const float*)s + off);
        uint2 o;
        o.x = (unsigned)f2bf(f.x) | ((unsigned)f2bf(f.y) << 16);
        o.y = (unsigned)f2bf(f.z) | ((unsigned)f2bf(f.w) << 16);
        *(uint2*)(dst + d) = o;
    }
}

// ---------------------------------------------------------------------------
// MFMA GEMM: C[m,n] = sum_k A[m,k]*W[n,k], A[M,1024], W[N,1024] bf16.
// 128x128 tile, BK=64, 4 waves 2x2 (each 64x64 = 4x4 mfma tiles).
// LDS in FRAGMENT ORDER (see r2 notes); all ds_read_b128 conflict-free.
// smode: 0 -> [B,H,T,DK]; 1 -> [H,PS,DK]; 2 -> [B,H,DK,T];
//        5 -> FUSED q|k|v epilogue (W = contiguous wq|wk|wv [3072,1024]);
//        6 -> row-major output, dtype by flag (bf16 if flag==0 else fp32) --
//             single launch replaces the old smode-3/4 pair.
// ---------------------------------------------------------------------------
__global__ __launch_bounds__(256, 3) void gemm_mfma(
    const int* __restrict__ flag,
    const ushort_t* __restrict__ A, const ushort_t* __restrict__ W,
    void* __restrict__ C, int smode)
{
    const int fl = flag[0];
    const int K = 1024, N = 1024;

    __shared__ ushort_t Al[16 * 512];   // 16 chunks x 512 ushorts (16KB)
    __shared__ ushort_t Wl[16 * 512];

    const int tid  = threadIdx.x;
    const int w    = tid >> 6, lane = tid & 63;
    const int r15  = lane & 15, quad = lane >> 4;
    const int wm   = w >> 1, wn = w & 1;
    const int m0   = blockIdx.y * 128, n0 = blockIdx.x * 128;

    floatx4 acc[4][4];
    const floatx4 z4 = {0.f, 0.f, 0.f, 0.f};
#pragma unroll
    for (int mt = 0; mt < 4; ++mt)
#pragma unroll
        for (int nt = 0; nt < 4; ++nt) acc[mt][nt] = z4;

    for (int k0 = 0; k0 < K; k0 += 64) {
        // stage: wave w stages chunks s = w*4 .. w*4+3 of both tiles
#pragma unroll
        for (int ss = 0; ss < 4; ++ss) {
            const int s  = w * 4 + ss;
            const int mg = s >> 1, ks = s & 1;
            const int row = mg * 16 + r15;
            const int col = k0 + ks * 32 + quad * 8;
            gload_lds16(A + (size_t)(m0 + row) * K + col, &Al[s * 512]);
            gload_lds16(W + (size_t)(n0 + row) * K + col, &Wl[s * 512]);
        }
        __syncthreads();

        short8 af[2][4], bf[2][4];
#pragma unroll
        for (int ks = 0; ks < 2; ++ks) {
#pragma unroll
            for (int mt = 0; mt < 4; ++mt)
                af[ks][mt] = *(const short8*)&Al[(((wm * 4 + mt) * 2 + ks) * 64 + lane) * 8];
#pragma unroll
            for (int nt = 0; nt < 4; ++nt)
                bf[ks][nt] = *(const short8*)&Wl[(((wn * 4 + nt) * 2 + ks) * 64 + lane) * 8];
        }
#pragma unroll
        for (int ks = 0; ks < 2; ++ks)
#pragma unroll
            for (int mt = 0; mt < 4; ++mt)
#pragma unroll
                for (int nt = 0; nt < 4; ++nt)
                    acc[mt][nt] = mfma16(af[ks][mt], bf[ks][nt], acc[mt][nt]);
        __syncthreads();
    }

    // epilogue (C-layout: row = quad*4+i, col = r15)
#pragma unroll
    for (int mt = 0; mt < 4; ++mt)
#pragma unroll
        for (int nt = 0; nt < 4; ++nt)
#pragma unroll
            for (int i = 0; i < 4; ++i) {
                const int m = m0 + wm * 64 + mt * 16 + quad * 4 + i;
                const int n = n0 + wn * 64 + nt * 16 + r15;
                const float v = acc[mt][nt][i];
                if (smode == 0) {
                    const int b = m >> 11, t = m & (T_ - 1);
                    const int h = n >> 7, dk = n & (DK_ - 1);
                    ((ushort_t*)C)[(((size_t)(b * H_ + h)) * T_ + t) * DK_ + dk] = f2bf(v);
                } else if (smode == 1) {
                    const int h = n >> 7, dk = n & (DK_ - 1);
                    ((ushort_t*)C)[((size_t)h * PS_ + m) * DK_ + dk] = f2bf(v);
                } else if (smode == 2) {
                    const int b = m >> 11, t = m & (T_ - 1);
                    const int h = n >> 7, dk = n & (DK_ - 1);
                    ((ushort_t*)C)[((size_t)(b * H_ + h) * DK_ + dk) * T_ + t] = f2bf(v);
                } else if (smode == 6) {
                    if (fl == 0)
                        ((ushort_t*)C)[(size_t)m * N + n] = f2bf(v);
                    else
                        ((float*)C)[(size_t)m * N + n] = v;
                } else {   // smode 5: fused q|k|v
                    const int b = m >> 11, t = m & (T_ - 1);
                    const int nn = n & 1023;
                    const int h = nn >> 7, dk = nn & (DK_ - 1);
                    const int wsel = n >> 10;          // 0=q, 1=k, 2=v
                    size_t idx;
                    if (wsel == 2)
                        idx = (size_t)16777216 + ((size_t)(b * H_ + h) * DK_ + dk) * T_ + t;
                    else
                        idx = (size_t)wsel * 8388608 +
                              (((size_t)(b * H_ + h)) * T_ + t) * DK_ + dk;
                    ((ushort_t*)C)[idx] = f2bf(v);
                }
            }
}

// ---------------------------------------------------------------------------
// MFMA flash attention, rel-shift folded:
//   score[q,k] = ((q+u)·K[k] + (q+v)·P[k-q+T-1]) / sqrt(DK)
// 4 waves x 16 q-rows, K-chunk 64. K (64x128), V^T (128x64) and the block's
// P band (128 rows) in LDS in FRAGMENT ORDER (ds_read_b128 = base+lane*16).
// Verified r2 body + r7's XCD swizzle, plus r8's one change:
//  * P SLIDING RING: the 128-row P band slides by 64 rows per iteration, so
//    half of each stage was redundant. Absolute row-group G (16 rows) lives
//    at slot G&7 permanently; iter 0 stages all 8 groups, iters n>=1 stage
//    only the 4 NEW groups (16KB not 32KB) into the slots vacated by the 4
//    expired ones. Vacated slots were last read during iter n-1's compute,
//    which finished before its end barrier -> overwrite at iter-n top is
//    race-free under the unchanged two-barrier skeleton. BD reads add
//    (+pring & 7) to the group index (wave-uniform).
//    Staged DMA drops 64 -> 48 KB per block-iter (-25%).
// LDS: 16+16+32+8 = 72KB -> 2 blocks/CU.
// ---------------------------------------------------------------------------
__global__ __launch_bounds__(256, 2) void attn_mfma(
    const ushort_t* __restrict__ qg,
    const ushort_t* __restrict__ kgl,
    const ushort_t* __restrict__ vt,   // [B,H,DK,T]
    const ushort_t* __restrict__ pg,   // [H,PS_,DK]
    const ushort_t* __restrict__ ubb,  // bf16 [H,DK]
    const ushort_t* __restrict__ vbb,
    ushort_t* __restrict__ ao)         // [B,T,D]
{
    __shared__ ushort_t K_lds[16 * 512];   // chunks (gk,ks) = gk*4+ks
    __shared__ ushort_t V_lds[16 * 512];   // chunks (og,ks2) = og*2+ks2
    __shared__ ushort_t P_lds[32 * 512];   // ring: slot s holds abs group G, s=G&7
    __shared__ __align__(16) ushort_t pr_lds[4][1024];  // per-wave A-frag tile

    const int tid  = threadIdx.x;
    const int w    = tid >> 6;
    const int lane = tid & 63;
    const int r15  = lane & 15;
    const int quad = lane >> 4;

    // XCD-aware bijective remap (1024 = 8 x 128; HW block i -> XCD i%8, so
    // XCD k serves swz ids k*128..k*128+127 = bh 4k..4k+3).
    const int lin  = (int)(blockIdx.y * 32 + blockIdx.x);
    const int swz  = (lin & 7) * 128 + (lin >> 3);
    const int bh   = swz >> 5;
    const int h    = bh & (H_ - 1);
    const int b    = bh >> 3;
    const int q0b  = (swz & 31) * 64;
    const int q0w  = q0b + w * 16;

    // Q fragments (A-layout) with u/v biases folded
    short8 quA[4], qvA[4];
    {
        const ushort_t* qrow = qg + ((size_t)bh * T_ + q0w + r15) * DK_;
#pragma unroll
        for (int ks = 0; ks < 4; ++ks) {
            const int dk0 = ks * 32 + quad * 8;
            uint4 q4 = *(const uint4*)(qrow + dk0);
            uint4 u4 = *(const uint4*)(ubb + (size_t)h * DK_ + dk0);
            uint4 v4 = *(const uint4*)(vbb + (size_t)h * DK_ + dk0);
            const ushort_t* qs = (const ushort_t*)&q4;
            const ushort_t* us = (const ushort_t*)&u4;
            const ushort_t* vs = (const ushort_t*)&v4;
#pragma unroll
            for (int j = 0; j < 8; ++j) {
                const float qf = bf2f(qs[j]);
                quA[ks][j] = (short)f2bf(qf + bf2f(us[j]));
                qvA[ks][j] = (short)f2bf(qf + bf2f(vs[j]));
            }
        }
    }

    // rel-shift gather lane sources (wave-static per i)
    int src[4], hi[4];
#pragma unroll
    for (int i = 0; i < 4; ++i) {
        const int c = r15 + 15 - quad * 4 - i;   // in [0,30]
        src[i] = quad * 16 + (c & 15);
        hi[i]  = c >> 4;                          // 0 or 1
    }

    floatx4 o[8];
    const floatx4 z4 = {0.f, 0.f, 0.f, 0.f};
#pragma unroll
    for (int g = 0; g < 8; ++g) o[g] = z4;
    floatx4 lacc = z4;                 // row sums (C-layout, same rows as o)
    float mrun[4];
#pragma unroll
    for (int i = 0; i < 4; ++i) mrun[i] = -1e30f;

    short8 ones8;
#pragma unroll
    for (int j = 0; j < 8; ++j) ones8[j] = (short)0x3F80;   // bf16 1.0

    const float scale = 0.08838834764831845f;  // 1/sqrt(128)

    // ring phase: abs group of band base at iter n is (1984-q0b)/16 + 4n;
    // pring = that & 7 (logical group g -> slot (g+pring)&7).
    int pring = (124 - (q0b >> 4)) & 7;

    const int NT = T_ / 64;
    for (int n = 0; n < NT; ++n) {
        const int kc0 = n * 64;
        const int pbb = kc0 - q0b + 1984;   // band base row (>=0, +127 <= 4095)

        // ---- stage K (4 chunks/wave) and V^T (4 chunks/wave) ----
#pragma unroll
        for (int ss = 0; ss < 4; ++ss) {
            const int ck = w * 4 + ss;            // (gk,ks) = (w, ss)
            gload_lds16(kgl + ((size_t)bh * T_ + kc0 + w * 16 + r15) * DK_ + ss * 32 + quad * 8,
                        &K_lds[ck * 512]);
            const int cv = w * 4 + ss;            // (og,ks2) = (cv>>1, cv&1)
            const int og = cv >> 1, ks2 = cv & 1;
            gload_lds16(vt + ((size_t)(bh * DK_ + og * 16 + r15)) * T_ + kc0 + ks2 * 32 + quad * 8,
                        &V_lds[cv * 512]);
        }
        // ---- stage P: full band at n=0, only the 4 new groups after ----
        if (n == 0) {
#pragma unroll
            for (int ss = 0; ss < 8; ++ss) {
                const int cp = w * 8 + ss;
                const int glog = cp >> 2, ks = cp & 3;
                const int slot = (glog + pring) & 7;
                gload_lds16(pg + ((size_t)h * PS_ + pbb + glog * 16 + r15) * DK_ + ks * 32 + quad * 8,
                            &P_lds[(slot * 4 + ks) * 512]);
            }
        } else {
#pragma unroll
            for (int ss = 0; ss < 4; ++ss) {
                const int cp = w * 4 + ss;
                const int glog = 4 + (cp >> 2), ks = cp & 3;
                const int slot = (glog + pring) & 7;
                gload_lds16(pg + ((size_t)h * PS_ + pbb + glog * 16 + r15) * DK_ + ks * 32 + quad * 8,
                            &P_lds[(slot * 4 + ks) * 512]);
            }
        }
        __syncthreads();

        // ---- AC = Qu x K^T ----
        floatx4 ac[4];
#pragma unroll
        for (int g = 0; g < 4; ++g) {
            ac[g] = z4;
#pragma unroll
            for (int ks = 0; ks < 4; ++ks)
                ac[g] = mfma16(quA[ks],
                               *(const short8*)&K_lds[((g * 4 + ks) * 64 + lane) * 8],
                               ac[g]);
        }
        // ---- BD band = Qv x P_band^T (wave window = groups (3-w)..(3-w)+4,
        //      ring-mapped to slots) ----
        floatx4 bd[5];
#pragma unroll
        for (int g = 0; g < 5; ++g) {
            bd[g] = z4;
            const int slot = ((3 - w) + g + pring) & 7;
#pragma unroll
            for (int ks = 0; ks < 4; ++ks)
                bd[g] = mfma16(qvA[ks],
                               *(const short8*)&P_lds[((slot * 4 + ks) * 64 + lane) * 8],
                               bd[g]);
        }

        // ---- scores: shift-gather via shfl; chunk max via DPP (VALU) ----
        float pr[4][4];
        float mc[4];
#pragma unroll
        for (int i = 0; i < 4; ++i) {
            float mm = -1e30f;
#pragma unroll
            for (int g = 0; g < 4; ++g) {
                const float lo = __shfl(bd[g][i],     src[i], 64);
                const float hh = __shfl(bd[g + 1][i], src[i], 64);
                const float s  = (ac[g][i] + (hi[i] ? hh : lo)) * scale;
                pr[g][i] = s;
                mm = fmaxf(mm, s);
            }
            mc[i] = rowmax16(mm);
        }
        // conditional rescale: only when some row's max grew (skip is exact:
        // otherwise mn==mrun and alpha==1 for every row)
        const bool nd = (mc[0] > mrun[0]) | (mc[1] > mrun[1]) |
                        (mc[2] > mrun[2]) | (mc[3] > mrun[3]);
        if (__any(nd)) {
            float alpha[4];
#pragma unroll
            for (int i = 0; i < 4; ++i) {
                const float mn = fmaxf(mrun[i], mc[i]);
                alpha[i] = __expf(mrun[i] - mn);
                mrun[i] = mn;
            }
#pragma unroll
            for (int g = 0; g < 8; ++g)
#pragma unroll
                for (int i = 0; i < 4; ++i) o[g][i] *= alpha[i];
#pragma unroll
            for (int i = 0; i < 4; ++i) lacc[i] *= alpha[i];
        }
#pragma unroll
        for (int g = 0; g < 4; ++g)
#pragma unroll
            for (int i = 0; i < 4; ++i)
                pr[g][i] = __expf(pr[g][i] - mrun[i]);

        // ---- probs C->A via per-wave fragment-ordered LDS ----
        // element (row=quad*4+i, col=g*16+r15): unit (ks2=g>>1, kq=(g&1)*2+(r15>>3))
#pragma unroll
        for (int g = 0; g < 4; ++g) {
            const int unit = (g >> 1) * 4 + (g & 1) * 2 + (r15 >> 3);
#pragma unroll
            for (int i = 0; i < 4; ++i)
                pr_lds[w][(unit * 16 + quad * 4 + i) * 8 + (r15 & 7)] = f2bf(pr[g][i]);
        }
        // wave-private region: compiler lgkmcnt ordering suffices (no barrier)
        short8 pa[2];
#pragma unroll
        for (int ks2 = 0; ks2 < 2; ++ks2)
            pa[ks2] = *(const short8*)&pr_lds[w][(ks2 * 64 + lane) * 8];

        // ---- PV: probs (A-layout) x V^T; row-sum rides along as mfma-ones ----
#pragma unroll
        for (int og = 0; og < 8; ++og)
#pragma unroll
            for (int ks2 = 0; ks2 < 2; ++ks2)
                o[og] = mfma16(pa[ks2],
                               *(const short8*)&V_lds[((og * 2 + ks2) * 64 + lane) * 8],
                               o[og]);
        lacc = mfma16(pa[0], ones8, lacc);
        lacc = mfma16(pa[1], ones8, lacc);
        __syncthreads();   // all waves done with K/V/P before restage
        pring = (pring + 4) & 7;
    }

    // ---- epilogue ----
    float inv[4];
#pragma unroll
    for (int i = 0; i < 4; ++i) inv[i] = 1.0f / lacc[i];
#pragma unroll
    for (int og = 0; og < 8; ++og)
#pragma unroll
        for (int i = 0; i < 4; ++i) {
            const size_t idx =
                ((size_t)(b * T_ + q0w + quad * 4 + i)) * D_ + h * DK_ + og * 16 + r15;
            ao[idx] = f2bf(o[og][i] * inv[i]);
        }
}

// ---------------------------------------------------------------------------
extern "C" void kernel_launch(void* const* d_in, const int* in_sizes, int n_in,
                              void* d_out, int out_size, void* d_ws, size_t ws_size,
                              hipStream_t stream) {
    const void* x  = d_in[0];
    const void* pe = d_in[1];
    const void* Wq = d_in[2];
    const void* Wk = d_in[3];
    const void* Wv = d_in[4];
    const void* Wo = d_in[5];
    const void* Wp = d_in[6];
    const void* ub = d_in[7];
    const void* vb = d_in[8];

    int* flag = (int*)d_ws;
    ushort_t* arena = (ushort_t*)d_ws + 16;   // +32 B
    ushort_t* xb   = arena;                    // 8,388,608   (reused as ao_ws)
    ushort_t* peb  = arena + 8388608;          // 4,194,304 (4096 rows, last = junk)
    ushort_t* wqb  = arena + 12582912;         // wq|wk|wv contiguous [3072,1024]
    ushort_t* wkb  = wqb + 1048576;
    ushort_t* wvb  = wkb + 1048576;
    ushort_t* wob  = wvb + 1048576;
    ushort_t* wpb  = wob + 1048576;
    ushort_t* ubb  = arena + 17825792;
    ushort_t* vbb  = ubb + 1024;
    ushort_t* q_ws  = arena + 17827840;        // q_ws|k_ws|vt_ws contiguous
    ushort_t* k_ws  = q_ws + 8388608;
    ushort_t* vt_ws = k_ws + 8388608;          // [B,H,DK,T]
    ushort_t* p_ws  = vt_ws + 8388608;         // [H,PS_,DK]
    ushort_t* ao_ws = xb;                      // x dead after q/k/v GEMMs

    detect_kernel<<<1, 64, 0, stream>>>((const ushort_t*)x, flag);

    const int cvb = CV_TOT / 4 / 256;          // 17409 exact
    convert_kernel<<<cvb, 256, 0, stream>>>(flag, x, pe, Wq, Wk, Wv, Wo, Wp, ub, vb, arena);

    // FUSED q|k|v projection: M=8192, N=3072 (weights contiguous), one launch.
    gemm_mfma<<<dim3(24, 64), 256, 0, stream>>>(flag, xb, wqb, q_ws, 5);
    // P projection: M=4096 (padded), N=1024.
    gemm_mfma<<<dim3(8, 32), 256, 0, stream>>>(flag, peb, wpb, p_ws, 1);

    attn_mfma<<<dim3(T_ / 64, B_ * H_), 256, 0, stream>>>(
        q_ws, k_ws, vt_ws, p_ws, ubb, vbb, ao_ws);

    // Output projection: single launch, output dtype chosen by flag.
    gemm_mfma<<<dim3(8, 64), 256, 0, stream>>>(flag, ao_ws, wob, d_out, 6);
}